// Round 4
// baseline (197.477 us; speedup 1.0000x reference)
//
#include <hip/hip_runtime.h>
#include <math.h>

#define D 128

__device__ __forceinline__ float softplusf(float z){
    return log1pf(expf(-fabsf(z))) + fmaxf(z, 0.f);
}
__device__ __forceinline__ unsigned short f2bf(float f){
    unsigned u = __float_as_uint(f);
    u += 0x7fffu + ((u >> 16) & 1u);          // round-to-nearest-even
    return (unsigned short)(u >> 16);
}

// ---- fused: pre (block 0) | xw16 = bf16(x @ W1) | deg count ----
__global__ void __launch_bounds__(256) k_fused1(
    const float* __restrict__ x, const float* __restrict__ W1,
    unsigned short* __restrict__ xw16, int N,
    const int* __restrict__ edst, int* __restrict__ deg, int E,
    int nGemm,
    const float* __restrict__ W2, const float* __restrict__ b2,
    const float* __restrict__ Wp, const float* __restrict__ bp,
    float* __restrict__ v, float* __restrict__ cconst)
{
    __shared__ float smem[32*D + 32*65];   // 24.7 KB
    const int b = blockIdx.x;
    const int tid = threadIdx.x;
    if (b == 0){
        // ---- pre: wave-per-row coalesced ----
        float* wps  = smem;        // [128]
        int lane = tid & 63, wid = tid >> 6;
        for (int r = wid; r < D; r += 4){
            float a = Wp[(size_t)r*D + lane] + Wp[(size_t)r*D + 64 + lane];
            for (int off=32; off>0; off>>=1) a += __shfl_down(a, off);
            if (lane == 0) wps[r] = a;
        }
        __syncthreads();
        float wl0 = wps[lane], wl1 = wps[64 + lane];
        for (int r = wid; r < D; r += 4){
            float a = W2[(size_t)r*D + lane]*wl0 + W2[(size_t)r*D + 64 + lane]*wl1;
            for (int off=32; off>0; off>>=1) a += __shfl_down(a, off);
            if (lane == 0) v[r] = a;
        }
        if (wid == 0){
            float a = b2[lane]*wl0 + b2[64+lane]*wl1 + bp[lane] + bp[64+lane];
            for (int off=32; off>0; off>>=1) a += __shfl_down(a, off);
            if (lane == 0) cconst[0] = a;
        }
    } else if (b <= nGemm){
        // ---- gemm: 64-row tile, transposed x panel ----
        float* Ws = smem;                                // [32][128]
        float (*xsT)[65] = (float(*)[65])(smem + 32*D);  // [k 32][row 64+pad]
        const int cg = tid & 31;
        const int rg = tid >> 5;                         // 0..7
        const int row0 = (b - 1) * 64;
        float4 acc[8];
        #pragma unroll
        for (int q=0;q<8;q++) acc[q] = make_float4(0.f,0.f,0.f,0.f);
        for (int p = 0; p < 4; ++p){
            int k0 = p*32;
            {   // W panel: 32k x 128
                int r = tid >> 5;
                int c = (tid & 31) * 4;
                #pragma unroll
                for (int s2 = 0; s2 < 4; ++s2){
                    int kk = r + s2*8;
                    *(float4*)&Ws[kk*D + c] = *(const float4*)&W1[(size_t)(k0+kk)*D + c];
                }
            }
            {   // x panel: 64 rows x 32 k, stored transposed
                int rr  = tid >> 2;             // 0..63
                int ccg = (tid & 3) * 8;        // 0,8,16,24
                int grow = row0 + rr;
                float4 va = make_float4(0.f,0.f,0.f,0.f);
                float4 vb = make_float4(0.f,0.f,0.f,0.f);
                if (grow < N){
                    va = *(const float4*)&x[(size_t)grow*D + k0 + ccg];
                    vb = *(const float4*)&x[(size_t)grow*D + k0 + ccg + 4];
                }
                xsT[ccg+0][rr] = va.x; xsT[ccg+1][rr] = va.y;
                xsT[ccg+2][rr] = va.z; xsT[ccg+3][rr] = va.w;
                xsT[ccg+4][rr] = vb.x; xsT[ccg+5][rr] = vb.y;
                xsT[ccg+6][rr] = vb.z; xsT[ccg+7][rr] = vb.w;
            }
            __syncthreads();
            #pragma unroll
            for (int kk = 0; kk < 32; ++kk){
                float4 w  = *(const float4*)&Ws[kk*D + cg*4];
                float4 xa = *(const float4*)&xsT[kk][rg*8];
                float4 xb = *(const float4*)&xsT[kk][rg*8 + 4];
                acc[0].x=fmaf(xa.x,w.x,acc[0].x); acc[0].y=fmaf(xa.x,w.y,acc[0].y); acc[0].z=fmaf(xa.x,w.z,acc[0].z); acc[0].w=fmaf(xa.x,w.w,acc[0].w);
                acc[1].x=fmaf(xa.y,w.x,acc[1].x); acc[1].y=fmaf(xa.y,w.y,acc[1].y); acc[1].z=fmaf(xa.y,w.z,acc[1].z); acc[1].w=fmaf(xa.y,w.w,acc[1].w);
                acc[2].x=fmaf(xa.z,w.x,acc[2].x); acc[2].y=fmaf(xa.z,w.y,acc[2].y); acc[2].z=fmaf(xa.z,w.z,acc[2].z); acc[2].w=fmaf(xa.z,w.w,acc[2].w);
                acc[3].x=fmaf(xa.w,w.x,acc[3].x); acc[3].y=fmaf(xa.w,w.y,acc[3].y); acc[3].z=fmaf(xa.w,w.z,acc[3].z); acc[3].w=fmaf(xa.w,w.w,acc[3].w);
                acc[4].x=fmaf(xb.x,w.x,acc[4].x); acc[4].y=fmaf(xb.x,w.y,acc[4].y); acc[4].z=fmaf(xb.x,w.z,acc[4].z); acc[4].w=fmaf(xb.x,w.w,acc[4].w);
                acc[5].x=fmaf(xb.y,w.x,acc[5].x); acc[5].y=fmaf(xb.y,w.y,acc[5].y); acc[5].z=fmaf(xb.y,w.z,acc[5].z); acc[5].w=fmaf(xb.y,w.w,acc[5].w);
                acc[6].x=fmaf(xb.z,w.x,acc[6].x); acc[6].y=fmaf(xb.z,w.y,acc[6].y); acc[6].z=fmaf(xb.z,w.z,acc[6].z); acc[6].w=fmaf(xb.z,w.w,acc[6].w);
                acc[7].x=fmaf(xb.w,w.x,acc[7].x); acc[7].y=fmaf(xb.w,w.y,acc[7].y); acc[7].z=fmaf(xb.w,w.z,acc[7].z); acc[7].w=fmaf(xb.w,w.w,acc[7].w);
            }
            __syncthreads();
        }
        #pragma unroll
        for (int q = 0; q < 8; ++q){
            int r = row0 + rg*8 + q;
            if (r < N){
                ushort4 o;
                o.x = f2bf(acc[q].x); o.y = f2bf(acc[q].y);
                o.z = f2bf(acc[q].z); o.w = f2bf(acc[q].w);
                *(ushort4*)&xw16[(size_t)r*D + cg*4] = o;
            }
        }
    } else {
        int e = (b - nGemm - 1)*256 + tid;
        if (e < E) atomicAdd(&deg[edst[e]], 1);
    }
}

// ---- exclusive scan of deg (1024/block) via wave shfl-scan ----
__global__ void k_scanA(const int* __restrict__ deg, int* __restrict__ offs,
                        int* __restrict__ bsum, int N){
    __shared__ int wsums[16];
    __shared__ int gtot;
    int tid = threadIdx.x, lane = tid & 63, wid = tid >> 6;
    int g = blockIdx.x*1024 + tid;
    int val = (g < N) ? deg[g] : 0;
    int inc = val;
    #pragma unroll
    for (int off=1; off<64; off<<=1){
        int t = __shfl_up(inc, off);
        if (lane >= off) inc += t;
    }
    if (lane == 63) wsums[wid] = inc;
    __syncthreads();
    if (wid == 0 && lane < 16){
        int t = wsums[lane];
        int i2 = t;
        #pragma unroll
        for (int off=1; off<16; off<<=1){
            int u = __shfl_up(i2, off);
            if (lane >= off) i2 += u;
        }
        wsums[lane] = i2 - t;           // exclusive
        if (lane == 15) gtot = i2;
    }
    __syncthreads();
    if (g < N) offs[g] = wsums[wid] + inc - val;
    if (tid == 0) bsum[blockIdx.x] = gtot;
}

// ---- finalize: cross-block prefix (nb<=64), offs, cursor, norm, ep ----
__global__ void k_scanC(int* __restrict__ offs, const int* __restrict__ bsum,
                        int* __restrict__ cursor, const int* __restrict__ deg,
                        float* __restrict__ norm, int2* __restrict__ ep,
                        const int* __restrict__ perm, int N){
    __shared__ int sbase;
    int tid = threadIdx.x;
    if (tid < 64){
        int val = (tid < (int)blockIdx.x) ? bsum[tid] : 0;
        for (int off=32; off>0; off>>=1) val += __shfl_down(val, off);
        if (tid == 0) sbase = val;
    }
    __syncthreads();
    int g = blockIdx.x*1024 + tid;
    if (g < N){
        int o = offs[g] + sbase;
        offs[g] = o;
        cursor[g] = o;
        float nm = rsqrtf(fmaxf((float)deg[g], 1.f));
        norm[g] = nm;
        ep[g] = make_int2(perm[g], __float_as_int(nm));
    }
}

// ---- fill CSR (src ids grouped by dst, uint16) ----
__global__ void k_fill(const int* __restrict__ src, const int* __restrict__ dst,
                       int* __restrict__ cursor, unsigned short* __restrict__ csr, int E){
    int e = blockIdx.x*blockDim.x + threadIdx.x;
    if (e < E){
        int dd = dst[e];
        int p = atomicAdd(&cursor[dd], 1);
        csr[p] = (unsigned short)src[e];
    }
}

#define FMA4(dv, nk) \
    ac.x = fmaf(__uint_as_float((dv).x << 16),          (nk), ac.x); \
    ac.y = fmaf(__uint_as_float((dv).x & 0xffff0000u),  (nk), ac.y); \
    ac.z = fmaf(__uint_as_float((dv).y << 16),          (nk), ac.z); \
    ac.w = fmaf(__uint_as_float((dv).y & 0xffff0000u),  (nk), ac.w);

// ---- fused layer-1 agg (clean lanes 0-31, corrupt lanes 32-63) + relu + dot(v) ----
__global__ void __launch_bounds__(256) k_agg(const unsigned short* __restrict__ xw16,
                     const unsigned short* __restrict__ csr, const int* __restrict__ offs,
                     const int* __restrict__ deg, const float* __restrict__ norm,
                     const int2* __restrict__ ep, const float* __restrict__ b1,
                     const float* __restrict__ v, float2* __restrict__ t2, int N){
    int w = threadIdx.x >> 6;
    int lane = threadIdx.x & 63;
    int i = blockIdx.x*4 + w;
    if (i >= N) return;
    int half = lane >> 5;
    int c = lane & 31;
    const uint2* __restrict__ xr = (const uint2*)xw16;    // row stride 32 uint2 (256B)
    float4 ac = make_float4(0.f,0.f,0.f,0.f);
    int start = offs[i], cnt = deg[i];

    for (int base = 0; base < cnt; base += 64){
        int m = min(cnt - base, 64);
        int s = 0, sp = 0; float ns = 0.f;
        if (lane < m){
            s = csr[start + base + lane];
            int2 e = ep[s];
            sp = e.x; ns = __int_as_float(e.y);
        }
        int k = 0;
        for (; k + 4 <= m; k += 4){
            int ra0=__shfl(s,k  ), rb0=__shfl(sp,k  ); float n0=__shfl(ns,k  );
            int ra1=__shfl(s,k+1), rb1=__shfl(sp,k+1); float n1=__shfl(ns,k+1);
            int ra2=__shfl(s,k+2), rb2=__shfl(sp,k+2); float n2=__shfl(ns,k+2);
            int ra3=__shfl(s,k+3), rb3=__shfl(sp,k+3); float n3=__shfl(ns,k+3);
            int r0 = half ? rb0 : ra0;
            int r1 = half ? rb1 : ra1;
            int r2 = half ? rb2 : ra2;
            int r3 = half ? rb3 : ra3;
            uint2 d0 = xr[(size_t)r0*32 + c];
            uint2 d1 = xr[(size_t)r1*32 + c];
            uint2 d2 = xr[(size_t)r2*32 + c];
            uint2 d3 = xr[(size_t)r3*32 + c];
            FMA4(d0, n0); FMA4(d1, n1); FMA4(d2, n2); FMA4(d3, n3);
        }
        for (; k < m; ++k){
            int ra=__shfl(s,k), rb=__shfl(sp,k); float nk=__shfl(ns,k);
            int r = half ? rb : ra;
            uint2 dv = xr[(size_t)r*32 + c];
            FMA4(dv, nk);
        }
    }
    float ni = norm[i];
    float4 bb = ((const float4*)b1)[c];
    float4 vv = ((const float4*)v)[c];
    float p = fmaxf(fmaf(ac.x, ni, bb.x), 0.f)*vv.x
            + fmaxf(fmaf(ac.y, ni, bb.y), 0.f)*vv.y
            + fmaxf(fmaf(ac.z, ni, bb.z), 0.f)*vv.z
            + fmaxf(fmaf(ac.w, ni, bb.w), 0.f)*vv.w;
    for (int off=16; off>0; off>>=1) p += __shfl_xor(p, off);
    float pd = __shfl(p, 32);
    if (lane == 0) t2[i] = make_float2(ni*p, ni*pd);
}

// ---- layer-2 scalar gather + loss + final (last-block) ----
__global__ void k_loss(const float2* __restrict__ t2, const unsigned short* __restrict__ csr,
                       const int* __restrict__ offs, const int* __restrict__ deg,
                       const float* __restrict__ norm, const float* __restrict__ cconst,
                       float* __restrict__ acc, unsigned* __restrict__ done,
                       float* __restrict__ out, int N, int nblocks){
    int i = blockIdx.x*blockDim.x + threadIdx.x;
    float li = 0.f;
    if (i < N){
        int start = offs[i], cnt = deg[i];
        float sc = 0.f, sd = 0.f;
        for (int k=0;k<cnt;k++){
            int s = csr[start+k];
            float2 t = t2[s];
            sc += t.x; sd += t.y;
        }
        float ni = norm[i], C = cconst[0];
        li = softplusf(-fmaf(ni, sc, C)) + softplusf(fmaf(ni, sd, C));
    }
    for (int off=32; off>0; off>>=1) li += __shfl_down(li, off);
    __shared__ float wsum[4];
    int lane = threadIdx.x & 63, wid = threadIdx.x >> 6;
    if (lane == 0) wsum[wid] = li;
    __syncthreads();
    if (threadIdx.x == 0){
        float s = wsum[0] + wsum[1] + wsum[2] + wsum[3];
        atomicAdd(acc, s);
        __threadfence();
        unsigned t = atomicAdd(done, 1u);
        if (t == (unsigned)(nblocks - 1)){
            float tot = atomicAdd(acc, 0.0f);
            out[0] = tot / (float)(2*N);
        }
    }
}

extern "C" void kernel_launch(void* const* d_in, const int* in_sizes, int n_in,
                              void* d_out, int out_size, void* d_ws, size_t ws_size,
                              hipStream_t stream){
    const float* x    = (const float*)d_in[0];
    const float* W1   = (const float*)d_in[1];
    const float* b1   = (const float*)d_in[2];
    const float* W2   = (const float*)d_in[3];
    const float* b2   = (const float*)d_in[4];
    const float* Wp   = (const float*)d_in[5];
    const float* bp   = (const float*)d_in[6];
    const int*   esrc = (const int*)d_in[7];
    const int*   edst = (const int*)d_in[8];
    const int*   perm = (const int*)d_in[9];
    const int N = in_sizes[0] / D;
    const int E = in_sizes[7];

    char* ws = (char*)d_ws;
    size_t off = 0;
    auto alloc = [&](size_t bytes)->void*{
        void* p = ws + off;
        off += (bytes + 255) & ~(size_t)255;
        return p;
    };
    unsigned short* xw16 = (unsigned short*)alloc((size_t)N*D*sizeof(unsigned short));
    int*   deg    = (int*)  alloc((size_t)N*sizeof(int));
    float* norm   = (float*)alloc((size_t)N*sizeof(float));
    int*   offs   = (int*)  alloc((size_t)N*sizeof(int));
    int*   cursor = (int*)  alloc((size_t)N*sizeof(int));
    int2*  ep     = (int2*) alloc((size_t)N*sizeof(int2));
    unsigned short* csr = (unsigned short*)alloc((size_t)E*sizeof(unsigned short));
    float2* t2    = (float2*)alloc((size_t)N*sizeof(float2));
    int*   bsum   = (int*)  alloc(4096);
    float* v      = (float*)alloc(D*sizeof(float));
    float* cconst = (float*)alloc(256);
    float* acc    = (float*)alloc(256);
    unsigned* done = (unsigned*)(acc + 1);

    hipMemsetAsync(deg, 0, (size_t)N*sizeof(int), stream);
    hipMemsetAsync(acc, 0, 256, stream);

    int nGemm = (N + 63) / 64;
    int nDeg  = (E + 255) / 256;
    int nb    = (N + 1023) / 1024;
    int nLoss = (N + 255) / 256;

    k_fused1<<<1 + nGemm + nDeg, 256, 0, stream>>>(x, W1, xw16, N, edst, deg, E,
                                                   nGemm, W2, b2, Wp, bp, v, cconst);
    k_scanA<<<nb, 1024, 0, stream>>>(deg, offs, bsum, N);
    k_scanC<<<nb, 1024, 0, stream>>>(offs, bsum, cursor, deg, norm, ep, perm, N);
    k_fill <<<(E+255)/256, 256, 0, stream>>>(esrc, edst, cursor, csr, E);
    k_agg  <<<(N+3)/4, 256, 0, stream>>>(xw16, csr, offs, deg, norm, ep, b1, v, t2, N);
    k_loss <<<nLoss, 256, 0, stream>>>(t2, csr, offs, deg, norm, cconst, acc, done,
                                       (float*)d_out, N, nLoss);
}

// Round 5
// 147.327 us; speedup vs baseline: 1.3404x; 1.3404x over previous
//
#include <hip/hip_runtime.h>
#include <math.h>

#define D 128

typedef float f32x2 __attribute__((ext_vector_type(2)));

__device__ __forceinline__ float softplusf(float z){
    return log1pf(expf(-fabsf(z))) + fmaxf(z, 0.f);
}

// ---- fused: pre (block 0) | xw8 = fp8(x @ W1) | deg count ----
__global__ void __launch_bounds__(256) k_fused1(
    const float* __restrict__ x, const float* __restrict__ W1,
    unsigned* __restrict__ xw8, int N,
    const int* __restrict__ edst, int* __restrict__ deg, int E,
    int nGemm,
    const float* __restrict__ W2, const float* __restrict__ b2,
    const float* __restrict__ Wp, const float* __restrict__ bp,
    float* __restrict__ v, float* __restrict__ cconst)
{
    __shared__ float smem[32*D + 32*36];   // 20.5 KB
    const int b = blockIdx.x;
    const int tid = threadIdx.x;
    if (b == 0){
        // ---- pre: wave-per-row coalesced ----
        float* wps = smem;        // [128]
        int lane = tid & 63, wid = tid >> 6;
        for (int r = wid; r < D; r += 4){
            float a = Wp[(size_t)r*D + lane] + Wp[(size_t)r*D + 64 + lane];
            for (int off=32; off>0; off>>=1) a += __shfl_down(a, off);
            if (lane == 0) wps[r] = a;
        }
        __syncthreads();
        float wl0 = wps[lane], wl1 = wps[64 + lane];
        for (int r = wid; r < D; r += 4){
            float a = W2[(size_t)r*D + lane]*wl0 + W2[(size_t)r*D + 64 + lane]*wl1;
            for (int off=32; off>0; off>>=1) a += __shfl_down(a, off);
            if (lane == 0) v[r] = a;
        }
        if (wid == 0){
            float a = b2[lane]*wl0 + b2[64+lane]*wl1 + bp[lane] + bp[64+lane];
            for (int off=32; off>0; off>>=1) a += __shfl_down(a, off);
            if (lane == 0) cconst[0] = a;
        }
    } else if (b <= nGemm){
        // ---- gemm: 32-row tile, 32-k LDS panels, 4x4 register tile (round-2 proven) ----
        float* Ws = smem;                                   // [32][128]
        float (*xs)[36] = (float(*)[36])(smem + 32*D);      // [32][32+pad]
        const int cg = tid & 31;
        const int rg = tid >> 5;
        int row0 = (b - 1) * 32;
        float4 acc[4];
        #pragma unroll
        for (int q=0;q<4;q++) acc[q] = make_float4(0.f,0.f,0.f,0.f);
        for (int p = 0; p < 4; ++p){
            int k0 = p*32;
            {
                int r = tid >> 5;
                int c = (tid & 31) * 4;
                #pragma unroll
                for (int s2 = 0; s2 < 4; ++s2){
                    int kk = r + s2*8;
                    *(float4*)&Ws[kk*D + c] = *(const float4*)&W1[(size_t)(k0+kk)*D + c];
                }
            }
            {
                int rr = tid >> 3;
                int cc = (tid & 7) * 4;
                int grow = row0 + rr;
                float4 vx = make_float4(0.f,0.f,0.f,0.f);
                if (grow < N) vx = *(const float4*)&x[(size_t)grow*D + k0 + cc];
                *(float4*)&xs[rr][cc] = vx;
            }
            __syncthreads();
            #pragma unroll
            for (int kk = 0; kk < 32; ++kk){
                float4 w = *(const float4*)&Ws[kk*D + cg*4];
                #pragma unroll
                for (int q = 0; q < 4; ++q){
                    float xv = xs[rg*4 + q][kk];
                    acc[q].x = fmaf(xv, w.x, acc[q].x);
                    acc[q].y = fmaf(xv, w.y, acc[q].y);
                    acc[q].z = fmaf(xv, w.z, acc[q].z);
                    acc[q].w = fmaf(xv, w.w, acc[q].w);
                }
            }
            __syncthreads();
        }
        #pragma unroll
        for (int q = 0; q < 4; ++q){
            int r = row0 + rg*4 + q;
            if (r < N){
                unsigned lo = (unsigned)__builtin_amdgcn_cvt_pk_fp8_f32(acc[q].x, acc[q].y, 0, false);
                unsigned u  = (unsigned)__builtin_amdgcn_cvt_pk_fp8_f32(acc[q].z, acc[q].w, (int)lo, true);
                xw8[(size_t)r*32 + cg] = u;
            }
        }
    } else {
        int e = (b - nGemm - 1)*256 + tid;
        if (e < E) atomicAdd(&deg[edst[e]], 1);
    }
}

// ---- exclusive scan of deg (1024/block) via wave shfl-scan ----
__global__ void k_scanA(const int* __restrict__ deg, int* __restrict__ offs,
                        int* __restrict__ bsum, int N){
    __shared__ int wsums[16];
    __shared__ int gtot;
    int tid = threadIdx.x, lane = tid & 63, wid = tid >> 6;
    int g = blockIdx.x*1024 + tid;
    int val = (g < N) ? deg[g] : 0;
    int inc = val;
    #pragma unroll
    for (int off=1; off<64; off<<=1){
        int t = __shfl_up(inc, off);
        if (lane >= off) inc += t;
    }
    if (lane == 63) wsums[wid] = inc;
    __syncthreads();
    if (wid == 0 && lane < 16){
        int t = wsums[lane];
        int i2 = t;
        #pragma unroll
        for (int off=1; off<16; off<<=1){
            int u = __shfl_up(i2, off);
            if (lane >= off) i2 += u;
        }
        wsums[lane] = i2 - t;           // exclusive
        if (lane == 15) gtot = i2;
    }
    __syncthreads();
    if (g < N) offs[g] = wsums[wid] + inc - val;
    if (tid == 0) bsum[blockIdx.x] = gtot;
}

// ---- finalize: cross-block prefix (nb<=64), offs, cursor, norm, ep ----
__global__ void k_scanC(int* __restrict__ offs, const int* __restrict__ bsum,
                        int* __restrict__ cursor, const int* __restrict__ deg,
                        float* __restrict__ norm, int2* __restrict__ ep,
                        const int* __restrict__ perm, int N){
    __shared__ int sbase;
    int tid = threadIdx.x;
    if (tid < 64){
        int val = (tid < (int)blockIdx.x) ? bsum[tid] : 0;
        for (int off=32; off>0; off>>=1) val += __shfl_down(val, off);
        if (tid == 0) sbase = val;
    }
    __syncthreads();
    int g = blockIdx.x*1024 + tid;
    if (g < N){
        int o = offs[g] + sbase;
        offs[g] = o;
        cursor[g] = o;
        float nm = rsqrtf(fmaxf((float)deg[g], 1.f));
        norm[g] = nm;
        ep[g] = make_int2(perm[g], __float_as_int(nm));
    }
}

// ---- fill CSR (src ids grouped by dst, uint16) ----
__global__ void k_fill(const int* __restrict__ src, const int* __restrict__ dst,
                       int* __restrict__ cursor, unsigned short* __restrict__ csr, int E){
    int e = blockIdx.x*blockDim.x + threadIdx.x;
    if (e < E){
        int dd = dst[e];
        int p = atomicAdd(&cursor[dd], 1);
        csr[p] = (unsigned short)src[e];
    }
}

#define FMA8(u, nk) { \
    f32x2 f01 = __builtin_amdgcn_cvt_pk_f32_fp8((int)(u), false); \
    f32x2 f23 = __builtin_amdgcn_cvt_pk_f32_fp8((int)(u), true);  \
    ac.x = fmaf(f01.x, (nk), ac.x); ac.y = fmaf(f01.y, (nk), ac.y); \
    ac.z = fmaf(f23.x, (nk), ac.z); ac.w = fmaf(f23.y, (nk), ac.w); }

// ---- fused layer-1 agg (clean lanes 0-31, corrupt lanes 32-63) + relu + dot(v) ----
__global__ void __launch_bounds__(256) k_agg(const unsigned* __restrict__ xw8,
                     const unsigned short* __restrict__ csr, const int* __restrict__ offs,
                     const int* __restrict__ deg, const float* __restrict__ norm,
                     const int2* __restrict__ ep, const float* __restrict__ b1,
                     const float* __restrict__ v, float2* __restrict__ t2, int N){
    int w = threadIdx.x >> 6;
    int lane = threadIdx.x & 63;
    int i = blockIdx.x*4 + w;
    if (i >= N) return;
    int half = lane >> 5;
    int c = lane & 31;                                // uint column (4 dims)
    const unsigned* __restrict__ xr = xw8;            // row stride 32 uints (128B)
    float4 ac = make_float4(0.f,0.f,0.f,0.f);
    int start = offs[i], cnt = deg[i];

    for (int base = 0; base < cnt; base += 64){
        int m = min(cnt - base, 64);
        int s = 0, sp = 0; float ns = 0.f;
        if (lane < m){
            s = csr[start + base + lane];
            int2 e = ep[s];
            sp = e.x; ns = __int_as_float(e.y);
        }
        int k = 0;
        for (; k + 4 <= m; k += 4){
            int ra0=__shfl(s,k  ), rb0=__shfl(sp,k  ); float n0=__shfl(ns,k  );
            int ra1=__shfl(s,k+1), rb1=__shfl(sp,k+1); float n1=__shfl(ns,k+1);
            int ra2=__shfl(s,k+2), rb2=__shfl(sp,k+2); float n2=__shfl(ns,k+2);
            int ra3=__shfl(s,k+3), rb3=__shfl(sp,k+3); float n3=__shfl(ns,k+3);
            int r0 = half ? rb0 : ra0;
            int r1 = half ? rb1 : ra1;
            int r2 = half ? rb2 : ra2;
            int r3 = half ? rb3 : ra3;
            unsigned d0 = xr[(size_t)r0*32 + c];
            unsigned d1 = xr[(size_t)r1*32 + c];
            unsigned d2 = xr[(size_t)r2*32 + c];
            unsigned d3 = xr[(size_t)r3*32 + c];
            FMA8(d0, n0); FMA8(d1, n1); FMA8(d2, n2); FMA8(d3, n3);
        }
        for (; k < m; ++k){
            int ra=__shfl(s,k), rb=__shfl(sp,k); float nk=__shfl(ns,k);
            int r = half ? rb : ra;
            unsigned dv = xr[(size_t)r*32 + c];
            FMA8(dv, nk);
        }
    }
    float ni = norm[i];
    float4 bb = ((const float4*)b1)[c];
    float4 vv = ((const float4*)v)[c];
    float p = fmaxf(fmaf(ac.x, ni, bb.x), 0.f)*vv.x
            + fmaxf(fmaf(ac.y, ni, bb.y), 0.f)*vv.y
            + fmaxf(fmaf(ac.z, ni, bb.z), 0.f)*vv.z
            + fmaxf(fmaf(ac.w, ni, bb.w), 0.f)*vv.w;
    for (int off=16; off>0; off>>=1) p += __shfl_xor(p, off);
    float pd = __shfl(p, 32);
    if (lane == 0) t2[i] = make_float2(ni*p, ni*pd);
}

// ---- layer-2 scalar gather + loss + final (last-block) ----
__global__ void k_loss(const float2* __restrict__ t2, const unsigned short* __restrict__ csr,
                       const int* __restrict__ offs, const int* __restrict__ deg,
                       const float* __restrict__ norm, const float* __restrict__ cconst,
                       float* __restrict__ acc, unsigned* __restrict__ done,
                       float* __restrict__ out, int N, int nblocks){
    int i = blockIdx.x*blockDim.x + threadIdx.x;
    float li = 0.f;
    if (i < N){
        int start = offs[i], cnt = deg[i];
        float sc = 0.f, sd = 0.f;
        for (int k=0;k<cnt;k++){
            int s = csr[start+k];
            float2 t = t2[s];
            sc += t.x; sd += t.y;
        }
        float ni = norm[i], C = cconst[0];
        li = softplusf(-fmaf(ni, sc, C)) + softplusf(fmaf(ni, sd, C));
    }
    for (int off=32; off>0; off>>=1) li += __shfl_down(li, off);
    __shared__ float wsum[4];
    int lane = threadIdx.x & 63, wid = threadIdx.x >> 6;
    if (lane == 0) wsum[wid] = li;
    __syncthreads();
    if (threadIdx.x == 0){
        float s = wsum[0] + wsum[1] + wsum[2] + wsum[3];
        atomicAdd(acc, s);
        __threadfence();
        unsigned t = atomicAdd(done, 1u);
        if (t == (unsigned)(nblocks - 1)){
            float tot = atomicAdd(acc, 0.0f);
            out[0] = tot / (float)(2*N);
        }
    }
}

extern "C" void kernel_launch(void* const* d_in, const int* in_sizes, int n_in,
                              void* d_out, int out_size, void* d_ws, size_t ws_size,
                              hipStream_t stream){
    const float* x    = (const float*)d_in[0];
    const float* W1   = (const float*)d_in[1];
    const float* b1   = (const float*)d_in[2];
    const float* W2   = (const float*)d_in[3];
    const float* b2   = (const float*)d_in[4];
    const float* Wp   = (const float*)d_in[5];
    const float* bp   = (const float*)d_in[6];
    const int*   esrc = (const int*)d_in[7];
    const int*   edst = (const int*)d_in[8];
    const int*   perm = (const int*)d_in[9];
    const int N = in_sizes[0] / D;
    const int E = in_sizes[7];

    char* ws = (char*)d_ws;
    size_t off = 0;
    auto alloc = [&](size_t bytes)->void*{
        void* p = ws + off;
        off += (bytes + 255) & ~(size_t)255;
        return p;
    };
    unsigned* xw8 = (unsigned*)alloc((size_t)N*32*sizeof(unsigned));   // fp8 rows, 128B
    int*   deg    = (int*)  alloc((size_t)N*sizeof(int));
    float* norm   = (float*)alloc((size_t)N*sizeof(float));
    int*   offs   = (int*)  alloc((size_t)N*sizeof(int));
    int*   cursor = (int*)  alloc((size_t)N*sizeof(int));
    int2*  ep     = (int2*) alloc((size_t)N*sizeof(int2));
    unsigned short* csr = (unsigned short*)alloc((size_t)E*sizeof(unsigned short));
    float2* t2    = (float2*)alloc((size_t)N*sizeof(float2));
    int*   bsum   = (int*)  alloc(4096);
    float* v      = (float*)alloc(D*sizeof(float));
    float* cconst = (float*)alloc(256);
    float* acc    = (float*)alloc(256);
    unsigned* done = (unsigned*)(acc + 1);

    hipMemsetAsync(deg, 0, (size_t)N*sizeof(int), stream);
    hipMemsetAsync(acc, 0, 256, stream);

    int nGemm = (N + 31) / 32;
    int nDeg  = (E + 255) / 256;
    int nb    = (N + 1023) / 1024;
    int nLoss = (N + 255) / 256;

    k_fused1<<<1 + nGemm + nDeg, 256, 0, stream>>>(x, W1, xw8, N, edst, deg, E,
                                                   nGemm, W2, b2, Wp, bp, v, cconst);
    k_scanA<<<nb, 1024, 0, stream>>>(deg, offs, bsum, N);
    k_scanC<<<nb, 1024, 0, stream>>>(offs, bsum, cursor, deg, norm, ep, perm, N);
    k_fill <<<(E+255)/256, 256, 0, stream>>>(esrc, edst, cursor, csr, E);
    k_agg  <<<(N+3)/4, 256, 0, stream>>>(xw8, csr, offs, deg, norm, ep, b1, v, t2, N);
    k_loss <<<nLoss, 256, 0, stream>>>(t2, csr, offs, deg, norm, cconst, acc, done,
                                       (float*)d_out, N, nLoss);
}

// Round 6
// 138.050 us; speedup vs baseline: 1.4305x; 1.0672x over previous
//
#include <hip/hip_runtime.h>
#include <math.h>

#define D 128

typedef float f32x2 __attribute__((ext_vector_type(2)));
typedef float f32x4 __attribute__((ext_vector_type(4)));
typedef short short8 __attribute__((ext_vector_type(8)));

__device__ __forceinline__ float softplusf(float z){
    return log1pf(expf(-fabsf(z))) + fmaxf(z, 0.f);
}
__device__ __forceinline__ unsigned short f2bf(float f){
    unsigned u = __float_as_uint(f);
    u += 0x7fffu + ((u >> 16) & 1u);          // round-to-nearest-even
    return (unsigned short)(u >> 16);
}
// swizzled LDS index (ushort units) for a [128 rows][128 bf16] tile:
// row stride 256B = 16 slots of 16B; slot ^= row&7 spreads banks.
__device__ __forceinline__ int wt_idx(int row, int k){
    return row*128 + ((((k >> 3) ^ (row & 7)) << 3) | (k & 7));
}

// ---- fused: pre (block 0) | xw8 = fp8(x @bf16 W1) via MFMA | deg count ----
__global__ void __launch_bounds__(256) k_fused1(
    const float* __restrict__ x, const float* __restrict__ W1,
    unsigned* __restrict__ xw8, int N,
    const int* __restrict__ edst, int* __restrict__ deg, int E,
    int nGemm,
    const float* __restrict__ W2, const float* __restrict__ b2,
    const float* __restrict__ Wp, const float* __restrict__ bp,
    float* __restrict__ v, float* __restrict__ cconst)
{
    __shared__ unsigned short Wt[128*128];   // 32 KB: W1^T bf16, swizzled
    __shared__ float pres[128];
    const int b = blockIdx.x;
    const int tid = threadIdx.x;
    if (b == 0){
        // ---- pre: wave-per-row coalesced ----
        float* wps = pres;
        int lane = tid & 63, wid = tid >> 6;
        for (int r = wid; r < D; r += 4){
            float a = Wp[(size_t)r*D + lane] + Wp[(size_t)r*D + 64 + lane];
            for (int off=32; off>0; off>>=1) a += __shfl_down(a, off);
            if (lane == 0) wps[r] = a;
        }
        __syncthreads();
        float wl0 = wps[lane], wl1 = wps[64 + lane];
        for (int r = wid; r < D; r += 4){
            float a = W2[(size_t)r*D + lane]*wl0 + W2[(size_t)r*D + 64 + lane]*wl1;
            for (int off=32; off>0; off>>=1) a += __shfl_down(a, off);
            if (lane == 0) v[r] = a;
        }
        if (wid == 0){
            float a = b2[lane]*wl0 + b2[64+lane]*wl1 + bp[lane] + bp[64+lane];
            for (int off=32; off>0; off>>=1) a += __shfl_down(a, off);
            if (lane == 0) cconst[0] = a;
        }
    } else if (b <= nGemm){
        // ---- MFMA gemm: 64 rows/block, wave w owns rows w*16..w*16+15 ----
        const int l = tid & 63, w = tid >> 6;
        const int row0 = (b - 1) * 64;
        // stage W1^T bf16 into LDS (8x8 lane tiles: conflict-free b16 writes)
        #pragma unroll 8
        for (int p = 0; p < 64; ++p){
            int ic = p & 15;                 // c-tile
            int ik = (p >> 4) + w*4;         // k-tile (wave-partitioned)
            int c = ic*8 + (l & 7);
            int k = ik*8 + (l >> 3);
            Wt[wt_idx(c, k)] = f2bf(W1[(size_t)k*D + c]);
        }
        // A-fragments straight from global (x has no block reuse)
        int arow = row0 + w*16 + (l & 15);
        int kbase = (l >> 4) * 8;
        short8 a[4];
        #pragma unroll
        for (int kc = 0; kc < 4; ++kc){
            float4 f0 = make_float4(0.f,0.f,0.f,0.f), f1 = f0;
            if (arow < N){
                const float* px = &x[(size_t)arow*D + kc*32 + kbase];
                f0 = *(const float4*)px;
                f1 = *(const float4*)(px + 4);
            }
            short8 av;
            av[0]=(short)f2bf(f0.x); av[1]=(short)f2bf(f0.y);
            av[2]=(short)f2bf(f0.z); av[3]=(short)f2bf(f0.w);
            av[4]=(short)f2bf(f1.x); av[5]=(short)f2bf(f1.y);
            av[6]=(short)f2bf(f1.z); av[7]=(short)f2bf(f1.w);
            a[kc] = av;
        }
        __syncthreads();
        int colg = (l & 15);
        #pragma unroll
        for (int nt = 0; nt < 8; ++nt){
            int col = nt*16 + colg;
            short8 bq[4];
            #pragma unroll
            for (int kc = 0; kc < 4; ++kc){
                int k0 = kc*32 + kbase;      // k0&7==0 -> 16B aligned slot
                bq[kc] = *(const short8*)&Wt[wt_idx(col, k0)];
            }
            f32x4 acc = {0.f, 0.f, 0.f, 0.f};
            #pragma unroll
            for (int kc = 0; kc < 4; ++kc)
                acc = __builtin_amdgcn_mfma_f32_16x16x32_bf16(a[kc], bq[kc], acc, 0, 0, 0);
            // epilogue: fp8-pack, byte stores (row = w*16 + (l>>4)*4 + reg)
            int rbase = row0 + w*16 + (l >> 4)*4;
            #pragma unroll
            for (int rp = 0; rp < 2; ++rp){
                int pk = __builtin_amdgcn_cvt_pk_fp8_f32(acc[rp*2], acc[rp*2+1], 0, false);
                int r0 = rbase + rp*2;
                if (r0 < N)     ((unsigned char*)xw8)[(size_t)r0*D + col]     = (unsigned char)(pk & 0xff);
                if (r0 + 1 < N) ((unsigned char*)xw8)[(size_t)(r0+1)*D + col] = (unsigned char)((pk >> 8) & 0xff);
            }
        }
    } else {
        int e = (b - nGemm - 1)*256 + tid;
        if (e < E) atomicAdd(&deg[edst[e]], 1);
    }
}

// ---- exclusive scan of deg (1024/block) via wave shfl-scan ----
__global__ void k_scanA(const int* __restrict__ deg, int* __restrict__ offs,
                        int* __restrict__ bsum, int N){
    __shared__ int wsums[16];
    __shared__ int gtot;
    int tid = threadIdx.x, lane = tid & 63, wid = tid >> 6;
    int g = blockIdx.x*1024 + tid;
    int val = (g < N) ? deg[g] : 0;
    int inc = val;
    #pragma unroll
    for (int off=1; off<64; off<<=1){
        int t = __shfl_up(inc, off);
        if (lane >= off) inc += t;
    }
    if (lane == 63) wsums[wid] = inc;
    __syncthreads();
    if (wid == 0 && lane < 16){
        int t = wsums[lane];
        int i2 = t;
        #pragma unroll
        for (int off=1; off<16; off<<=1){
            int u = __shfl_up(i2, off);
            if (lane >= off) i2 += u;
        }
        wsums[lane] = i2 - t;           // exclusive
        if (lane == 15) gtot = i2;
    }
    __syncthreads();
    if (g < N) offs[g] = wsums[wid] + inc - val;
    if (tid == 0) bsum[blockIdx.x] = gtot;
}

// ---- finalize: cross-block prefix (nb<=64), offs, cursor, norm, ep ----
__global__ void k_scanC(int* __restrict__ offs, const int* __restrict__ bsum,
                        int* __restrict__ cursor, const int* __restrict__ deg,
                        float* __restrict__ norm, int2* __restrict__ ep,
                        const int* __restrict__ perm, int N){
    __shared__ int sbase;
    int tid = threadIdx.x;
    if (tid < 64){
        int val = (tid < (int)blockIdx.x) ? bsum[tid] : 0;
        for (int off=32; off>0; off>>=1) val += __shfl_down(val, off);
        if (tid == 0) sbase = val;
    }
    __syncthreads();
    int g = blockIdx.x*1024 + tid;
    if (g < N){
        int o = offs[g] + sbase;
        offs[g] = o;
        cursor[g] = o;
        float nm = rsqrtf(fmaxf((float)deg[g], 1.f));
        norm[g] = nm;
        ep[g] = make_int2(perm[g], __float_as_int(nm));
    }
}

// ---- fill CSR (src ids grouped by dst, uint16) ----
__global__ void k_fill(const int* __restrict__ src, const int* __restrict__ dst,
                       int* __restrict__ cursor, unsigned short* __restrict__ csr, int E){
    int e = blockIdx.x*blockDim.x + threadIdx.x;
    if (e < E){
        int dd = dst[e];
        int p = atomicAdd(&cursor[dd], 1);
        csr[p] = (unsigned short)src[e];
    }
}

#define FMA8(u, nk) { \
    f32x2 f01 = __builtin_amdgcn_cvt_pk_f32_fp8((int)(u), false); \
    f32x2 f23 = __builtin_amdgcn_cvt_pk_f32_fp8((int)(u), true);  \
    ac.x = fmaf(f01.x, (nk), ac.x); ac.y = fmaf(f01.y, (nk), ac.y); \
    ac.z = fmaf(f23.x, (nk), ac.z); ac.w = fmaf(f23.y, (nk), ac.w); }

// ---- fused layer-1 agg (clean lanes 0-31, corrupt lanes 32-63) + relu + dot(v) ----
__global__ void __launch_bounds__(256) k_agg(const unsigned* __restrict__ xw8,
                     const unsigned short* __restrict__ csr, const int* __restrict__ offs,
                     const int* __restrict__ deg, const float* __restrict__ norm,
                     const int2* __restrict__ ep, const float* __restrict__ b1,
                     const float* __restrict__ v, float2* __restrict__ t2, int N){
    int w = threadIdx.x >> 6;
    int lane = threadIdx.x & 63;
    int i = blockIdx.x*4 + w;
    if (i >= N) return;
    int half = lane >> 5;
    int c = lane & 31;                                // uint column (4 dims)
    const unsigned* __restrict__ xr = xw8;            // row stride 32 uints (128B)
    float4 ac = make_float4(0.f,0.f,0.f,0.f);
    int start = offs[i], cnt = deg[i];

    for (int base = 0; base < cnt; base += 64){
        int m = min(cnt - base, 64);
        int s = 0, sp = 0; float ns = 0.f;
        if (lane < m){
            s = csr[start + base + lane];
            int2 e = ep[s];
            sp = e.x; ns = __int_as_float(e.y);
        }
        int k = 0;
        for (; k + 4 <= m; k += 4){
            int ra0=__shfl(s,k  ), rb0=__shfl(sp,k  ); float n0=__shfl(ns,k  );
            int ra1=__shfl(s,k+1), rb1=__shfl(sp,k+1); float n1=__shfl(ns,k+1);
            int ra2=__shfl(s,k+2), rb2=__shfl(sp,k+2); float n2=__shfl(ns,k+2);
            int ra3=__shfl(s,k+3), rb3=__shfl(sp,k+3); float n3=__shfl(ns,k+3);
            int r0 = half ? rb0 : ra0;
            int r1 = half ? rb1 : ra1;
            int r2 = half ? rb2 : ra2;
            int r3 = half ? rb3 : ra3;
            unsigned d0 = xr[(size_t)r0*32 + c];
            unsigned d1 = xr[(size_t)r1*32 + c];
            unsigned d2 = xr[(size_t)r2*32 + c];
            unsigned d3 = xr[(size_t)r3*32 + c];
            FMA8(d0, n0); FMA8(d1, n1); FMA8(d2, n2); FMA8(d3, n3);
        }
        for (; k < m; ++k){
            int ra=__shfl(s,k), rb=__shfl(sp,k); float nk=__shfl(ns,k);
            int r = half ? rb : ra;
            unsigned dv = xr[(size_t)r*32 + c];
            FMA8(dv, nk);
        }
    }
    float ni = norm[i];
    float4 bb = ((const float4*)b1)[c];
    float4 vv = ((const float4*)v)[c];
    float p = fmaxf(fmaf(ac.x, ni, bb.x), 0.f)*vv.x
            + fmaxf(fmaf(ac.y, ni, bb.y), 0.f)*vv.y
            + fmaxf(fmaf(ac.z, ni, bb.z), 0.f)*vv.z
            + fmaxf(fmaf(ac.w, ni, bb.w), 0.f)*vv.w;
    for (int off=16; off>0; off>>=1) p += __shfl_xor(p, off);
    float pd = __shfl(p, 32);
    if (lane == 0) t2[i] = make_float2(ni*p, ni*pd);
}

// ---- layer-2 scalar gather + loss + final (last-block) ----
__global__ void k_loss(const float2* __restrict__ t2, const unsigned short* __restrict__ csr,
                       const int* __restrict__ offs, const int* __restrict__ deg,
                       const float* __restrict__ norm, const float* __restrict__ cconst,
                       float* __restrict__ acc, unsigned* __restrict__ done,
                       float* __restrict__ out, int N, int nblocks){
    int i = blockIdx.x*blockDim.x + threadIdx.x;
    float li = 0.f;
    if (i < N){
        int start = offs[i], cnt = deg[i];
        float sc = 0.f, sd = 0.f;
        for (int k=0;k<cnt;k++){
            int s = csr[start+k];
            float2 t = t2[s];
            sc += t.x; sd += t.y;
        }
        float ni = norm[i], C = cconst[0];
        li = softplusf(-fmaf(ni, sc, C)) + softplusf(fmaf(ni, sd, C));
    }
    for (int off=32; off>0; off>>=1) li += __shfl_down(li, off);
    __shared__ float wsum[4];
    int lane = threadIdx.x & 63, wid = threadIdx.x >> 6;
    if (lane == 0) wsum[wid] = li;
    __syncthreads();
    if (threadIdx.x == 0){
        float s = wsum[0] + wsum[1] + wsum[2] + wsum[3];
        atomicAdd(acc, s);
        __threadfence();
        unsigned t = atomicAdd(done, 1u);
        if (t == (unsigned)(nblocks - 1)){
            float tot = atomicAdd(acc, 0.0f);
            out[0] = tot / (float)(2*N);
        }
    }
}

extern "C" void kernel_launch(void* const* d_in, const int* in_sizes, int n_in,
                              void* d_out, int out_size, void* d_ws, size_t ws_size,
                              hipStream_t stream){
    const float* x    = (const float*)d_in[0];
    const float* W1   = (const float*)d_in[1];
    const float* b1   = (const float*)d_in[2];
    const float* W2   = (const float*)d_in[3];
    const float* b2   = (const float*)d_in[4];
    const float* Wp   = (const float*)d_in[5];
    const float* bp   = (const float*)d_in[6];
    const int*   esrc = (const int*)d_in[7];
    const int*   edst = (const int*)d_in[8];
    const int*   perm = (const int*)d_in[9];
    const int N = in_sizes[0] / D;
    const int E = in_sizes[7];

    char* ws = (char*)d_ws;
    size_t off = 0;
    auto alloc = [&](size_t bytes)->void*{
        void* p = ws + off;
        off += (bytes + 255) & ~(size_t)255;
        return p;
    };
    unsigned* xw8 = (unsigned*)alloc((size_t)N*32*sizeof(unsigned));   // fp8 rows, 128B
    int*   deg    = (int*)  alloc((size_t)N*sizeof(int));
    float* norm   = (float*)alloc((size_t)N*sizeof(float));
    int*   offs   = (int*)  alloc((size_t)N*sizeof(int));
    int*   cursor = (int*)  alloc((size_t)N*sizeof(int));
    int2*  ep     = (int2*) alloc((size_t)N*sizeof(int2));
    unsigned short* csr = (unsigned short*)alloc((size_t)E*sizeof(unsigned short));
    float2* t2    = (float2*)alloc((size_t)N*sizeof(float2));
    int*   bsum   = (int*)  alloc(4096);
    float* v      = (float*)alloc(D*sizeof(float));
    float* cconst = (float*)alloc(256);
    float* acc    = (float*)alloc(256);
    unsigned* done = (unsigned*)(acc + 1);

    hipMemsetAsync(deg, 0, (size_t)N*sizeof(int), stream);
    hipMemsetAsync(acc, 0, 256, stream);

    int nGemm = (N + 63) / 64;
    int nDeg  = (E + 255) / 256;
    int nb    = (N + 1023) / 1024;
    int nLoss = (N + 255) / 256;

    k_fused1<<<1 + nGemm + nDeg, 256, 0, stream>>>(x, W1, xw8, N, edst, deg, E,
                                                   nGemm, W2, b2, Wp, bp, v, cconst);
    k_scanA<<<nb, 1024, 0, stream>>>(deg, offs, bsum, N);
    k_scanC<<<nb, 1024, 0, stream>>>(offs, bsum, cursor, deg, norm, ep, perm, N);
    k_fill <<<(E+255)/256, 256, 0, stream>>>(esrc, edst, cursor, csr, E);
    k_agg  <<<(N+3)/4, 256, 0, stream>>>(xw8, csr, offs, deg, norm, ep, b1, v, t2, N);
    k_loss <<<nLoss, 256, 0, stream>>>(t2, csr, offs, deg, norm, cconst, acc, done,
                                       (float*)d_out, N, nLoss);
}